// Round 4
// baseline (997.170 us; speedup 1.0000x reference)
//
#include <hip/hip_runtime.h>

#define TPB 256

// ---------------------------------------------------------------------------
// Edge dtype handling: reference declares int64 edge_index, but harness may
// stage int32. Detect on device: if data is int64 (values < 2^31), every odd
// int32 word in the first 2E words (high words of the src row) is zero.
// flag != 0  =>  int32 data.
// ---------------------------------------------------------------------------
static __device__ __forceinline__ int edge_val(const int* __restrict__ ep,
                                               long long idx, int is64) {
  return is64 ? ep[2 * idx] : ep[idx];
}

__global__ void k_detect(const int* __restrict__ ep, long long n32,
                         int* __restrict__ flag) {
  long long stride = (long long)gridDim.x * blockDim.x;
  int found = 0;
  for (long long i = blockIdx.x * (long long)blockDim.x + threadIdx.x;
       2 * i + 1 < n32; i += stride)
    found |= (ep[2 * i + 1] != 0);
  if (found) atomicOr(flag, 1);
}

// deg[dst]++ over all edges (in-degree; self-loop added later as +1)
__global__ void k_count(const int* __restrict__ ep, long long E,
                        const int* __restrict__ flag, int* __restrict__ deg) {
  int is64 = (*flag == 0);
  long long stride = (long long)gridDim.x * blockDim.x;
  for (long long e = blockIdx.x * (long long)blockDim.x + threadIdx.x; e < E;
       e += stride) {
    int d = edge_val(ep, E + e, is64);
    atomicAdd(&deg[d], 1);
  }
}

// per-block sums of deg for the 2-level scan
__global__ void k_bsum(const int* __restrict__ deg, int N,
                       int* __restrict__ bsums) {
  __shared__ int lds[TPB];
  int t = threadIdx.x;
  int i = blockIdx.x * TPB + t;
  lds[t] = (i < N) ? deg[i] : 0;
  __syncthreads();
  for (int off = TPB / 2; off > 0; off >>= 1) {
    if (t < off) lds[t] += lds[t + off];
    __syncthreads();
  }
  if (t == 0) bsums[blockIdx.x] = lds[0];
}

// single-block exclusive scan of the block sums (nb <= 512)
__global__ void k_bscan(int* __restrict__ bsums, int nb) {
  __shared__ int lds[512];
  int t = threadIdx.x;
  int v = (t < nb) ? bsums[t] : 0;
  lds[t] = v;
  __syncthreads();
  for (int off = 1; off < 512; off <<= 1) {
    int x = (t >= off) ? lds[t - off] : 0;
    __syncthreads();
    lds[t] += x;
    __syncthreads();
  }
  if (t < nb) bsums[t] = lds[t] - v;  // exclusive
}

// in-block exclusive scan + block offset -> row_start, cursor; also r = rsqrt(deg+1)
__global__ void k_scan3(const int* __restrict__ deg, const int* __restrict__ bsums,
                        int N, int* __restrict__ row_start, int* __restrict__ cursor,
                        float* __restrict__ r) {
  __shared__ int lds[TPB];
  int t = threadIdx.x;
  int i = blockIdx.x * TPB + t;
  int v = (i < N) ? deg[i] : 0;
  lds[t] = v;
  __syncthreads();
  for (int off = 1; off < TPB; off <<= 1) {
    int x = (t >= off) ? lds[t - off] : 0;
    __syncthreads();
    lds[t] += x;
    __syncthreads();
  }
  if (i < N) {
    int ex = lds[t] - v + bsums[blockIdx.x];
    row_start[i] = ex;
    cursor[i] = ex;
    r[i] = rsqrtf((float)(v + 1));
  }
}

// scatter edge src ids into CSR-by-dst
__global__ void k_fill(const int* __restrict__ ep, long long E,
                       const int* __restrict__ flag, int* __restrict__ cursor,
                       int* __restrict__ csr_src) {
  int is64 = (*flag == 0);
  long long stride = (long long)gridDim.x * blockDim.x;
  for (long long e = blockIdx.x * (long long)blockDim.x + threadIdx.x; e < E;
       e += stride) {
    int s = edge_val(ep, e, is64);
    int d = edge_val(ep, E + e, is64);
    int pos = atomicAdd(&cursor[d], 1);
    csr_src[pos] = s;
  }
}

// out[row,:] = (X[row,:] @ W) * r[row]   (W: [128,128] row-major, in LDS)
__global__ __launch_bounds__(TPB) void k_gemm_scale(
    const float* __restrict__ X, const float* __restrict__ W,
    const float* __restrict__ r, float* __restrict__ out, int N) {
  __shared__ float wl[128 * 128];
  for (int i = threadIdx.x; i < 128 * 128 / 4; i += TPB)
    reinterpret_cast<float4*>(wl)[i] = reinterpret_cast<const float4*>(W)[i];
  __syncthreads();
  int wave = threadIdx.x >> 6, lane = threadIdx.x & 63;
  int row0 = (blockIdx.x * 4 + wave) * 8;
  if (row0 >= N) return;
  const int c0 = lane * 2;
  float2 acc[8];
#pragma unroll
  for (int q = 0; q < 8; q++) acc[q] = make_float2(0.f, 0.f);
  for (int kk = 0; kk < 128; kk += 4) {
    float4 xv[8];
#pragma unroll
    for (int q = 0; q < 8; q++) {
      int rr = row0 + q;
      if (rr >= N) rr = N - 1;
      xv[q] = *reinterpret_cast<const float4*>(&X[(size_t)rr * 128 + kk]);
    }
#pragma unroll
    for (int u = 0; u < 4; u++) {
      float2 w = *reinterpret_cast<const float2*>(&wl[(kk + u) * 128 + c0]);
#pragma unroll
      for (int q = 0; q < 8; q++) {
        float xk = (u == 0) ? xv[q].x : (u == 1) ? xv[q].y : (u == 2) ? xv[q].z
                                                                     : xv[q].w;
        acc[q].x = fmaf(xk, w.x, acc[q].x);
        acc[q].y = fmaf(xk, w.y, acc[q].y);
      }
    }
  }
#pragma unroll
  for (int q = 0; q < 8; q++) {
    int rr = row0 + q;
    if (rr < N) {
      float sc = r[rr];
      *reinterpret_cast<float2*>(&out[(size_t)rr * 128 + c0]) =
          make_float2(acc[q].x * sc, acc[q].y * sc);
    }
  }
}

// aggregation: out[i] = act( r[i]*(Hs[i] + sum_{src->i} Hs[src]) + b )
// RELU: apply relu and store to `out`.  COLSUM: no store, accumulate column sums.
template <int RELU, int COLSUM>
__global__ __launch_bounds__(TPB) void k_agg(
    const float* __restrict__ Hs, const float* __restrict__ r,
    const int* __restrict__ row_start, const int* __restrict__ deg,
    const int* __restrict__ csr_src, const float* __restrict__ bias,
    float* __restrict__ out, float* __restrict__ colsum, int N) {
  int wave = threadIdx.x >> 6, lane = threadIdx.x & 63;
  int gw = blockIdx.x * 4 + wave;
  int nw = gridDim.x * 4;
  const int c0 = lane * 2;
  float2 b = *reinterpret_cast<const float2*>(&bias[c0]);
  float2 csum = make_float2(0.f, 0.f);
  for (int i = gw; i < N; i += nw) {
    float2 acc = *reinterpret_cast<const float2*>(&Hs[(size_t)i * 128 + c0]);
    int start = row_start[i];
    int d = deg[i];
    int j = 0;
    for (; j + 4 <= d; j += 4) {
      int s0 = csr_src[start + j + 0];
      int s1 = csr_src[start + j + 1];
      int s2 = csr_src[start + j + 2];
      int s3 = csr_src[start + j + 3];
      float2 v0 = *reinterpret_cast<const float2*>(&Hs[(size_t)s0 * 128 + c0]);
      float2 v1 = *reinterpret_cast<const float2*>(&Hs[(size_t)s1 * 128 + c0]);
      float2 v2 = *reinterpret_cast<const float2*>(&Hs[(size_t)s2 * 128 + c0]);
      float2 v3 = *reinterpret_cast<const float2*>(&Hs[(size_t)s3 * 128 + c0]);
      acc.x += (v0.x + v1.x) + (v2.x + v3.x);
      acc.y += (v0.y + v1.y) + (v2.y + v3.y);
    }
    for (; j < d; j++) {
      int s = csr_src[start + j];
      float2 v = *reinterpret_cast<const float2*>(&Hs[(size_t)s * 128 + c0]);
      acc.x += v.x;
      acc.y += v.y;
    }
    float ri = r[i];
    float2 val = make_float2(fmaf(ri, acc.x, b.x), fmaf(ri, acc.y, b.y));
    if (RELU) {
      val.x = fmaxf(val.x, 0.f);
      val.y = fmaxf(val.y, 0.f);
    }
    if (COLSUM) {
      csum.x += val.x;
      csum.y += val.y;
    } else {
      *reinterpret_cast<float2*>(&out[(size_t)i * 128 + c0]) = val;
    }
  }
  if (COLSUM) {
    __shared__ float red[4][128];
    red[wave][c0] = csum.x;
    red[wave][c0 + 1] = csum.y;
    __syncthreads();
    if (wave == 0) {
      float sx = red[0][c0] + red[1][c0] + red[2][c0] + red[3][c0];
      float sy = red[0][c0 + 1] + red[1][c0 + 1] + red[2][c0 + 1] + red[3][c0 + 1];
      atomicAdd(&colsum[c0], sx);
      atomicAdd(&colsum[c0 + 1], sy);
    }
  }
}

__global__ void k_final(const float* __restrict__ colsum, float* __restrict__ out,
                        float invN) {
  int c = threadIdx.x;
  out[c] = colsum[c] * invN;
}

extern "C" void kernel_launch(void* const* d_in, const int* in_sizes, int n_in,
                              void* d_out, int out_size, void* d_ws, size_t ws_size,
                              hipStream_t stream) {
  const float* x = (const float*)d_in[0];
  const int* ep = (const int*)d_in[1];
  const float* W1 = (const float*)d_in[2];
  const float* b1 = (const float*)d_in[3];
  const float* W2 = (const float*)d_in[4];
  const float* b2 = (const float*)d_in[5];
  float* outp = (float*)d_out;

  const int N = in_sizes[0] / 128;        // 100000
  const long long E = in_sizes[1] / 2;    // 1600000
  const long long n32 = in_sizes[1];      // flat element count of edge_index

  // ---- workspace carve (aligned 256B) -------------------------------------
  char* ws = (char*)d_ws;
  size_t off = 0;
  auto carve = [&](size_t bytes) -> void* {
    void* p = ws + off;
    off = (off + bytes + 255) & ~(size_t)255;
    return p;
  };
  float* Hs = (float*)carve((size_t)N * 128 * 4);   // 51.2 MB
  float* Y = (float*)carve((size_t)N * 128 * 4);    // 51.2 MB
  float* rr = (float*)carve((size_t)N * 4);
  int* deg = (int*)carve((size_t)N * 4);
  int* rs = (int*)carve((size_t)N * 4);
  int* cur = (int*)carve((size_t)N * 4);
  int* csr = (int*)carve((size_t)E * 4);            // 6.4 MB
  int* bsums = (int*)carve(4096 * 4);
  int* flag = (int*)carve(256);
  float* colsum = (float*)carve(512);

  hipMemsetAsync(flag, 0, 4, stream);
  hipMemsetAsync(deg, 0, (size_t)N * 4, stream);
  hipMemsetAsync(colsum, 0, 512, stream);

  k_detect<<<2048, TPB, 0, stream>>>(ep, n32, flag);
  k_count<<<2048, TPB, 0, stream>>>(ep, E, flag, deg);
  int nb = (N + TPB - 1) / TPB;  // 391 <= 512
  k_bsum<<<nb, TPB, 0, stream>>>(deg, N, bsums);
  k_bscan<<<1, 512, 0, stream>>>(bsums, nb);
  k_scan3<<<nb, TPB, 0, stream>>>(deg, bsums, N, rs, cur, rr);
  k_fill<<<2048, TPB, 0, stream>>>(ep, E, flag, cur, csr);

  int gblocks = (N + 31) / 32;
  k_gemm_scale<<<gblocks, TPB, 0, stream>>>(x, W1, rr, Hs, N);
  k_agg<1, 0><<<2048, TPB, 0, stream>>>(Hs, rr, rs, deg, csr, b1, Y, nullptr, N);
  k_gemm_scale<<<gblocks, TPB, 0, stream>>>(Y, W2, rr, Hs, N);
  k_agg<0, 1><<<2048, TPB, 0, stream>>>(Hs, rr, rs, deg, csr, b2, nullptr, colsum, N);
  k_final<<<1, 128, 0, stream>>>(colsum, outp, 1.0f / (float)N);
}

// Round 6
// 881.017 us; speedup vs baseline: 1.1318x; 1.1318x over previous
//
#include <hip/hip_runtime.h>

#define TPB 256

// ---------------------------------------------------------------------------
// bf16 helpers (RTNE, bit-level; no header dependency)
// ---------------------------------------------------------------------------
static __device__ __forceinline__ unsigned short f2bf(float f) {
  unsigned int u = __float_as_uint(f);
  unsigned int r = (u + 0x7FFFu + ((u >> 16) & 1u)) >> 16;
  return (unsigned short)r;
}
static __device__ __forceinline__ float bf_lo(unsigned int v) {
  return __uint_as_float(v << 16);
}
static __device__ __forceinline__ float bf_hi(unsigned int v) {
  return __uint_as_float(v & 0xFFFF0000u);
}

// ---------------------------------------------------------------------------
// Edge dtype handling: reference declares int64 edge_index, but harness may
// stage int32. If data is int64 (node ids < 2^31), every odd int32 word of
// the src row is zero. flag != 0  =>  int32 data.
// ---------------------------------------------------------------------------
static __device__ __forceinline__ int edge_val(const int* __restrict__ ep,
                                               long long idx, int is64) {
  return is64 ? ep[2 * idx] : ep[idx];
}

__global__ void k_detect(const int* __restrict__ ep, long long n32,
                         int* __restrict__ flag) {
  long long stride = (long long)gridDim.x * blockDim.x;
  int found = 0;
  for (long long i = blockIdx.x * (long long)blockDim.x + threadIdx.x;
       2 * i + 1 < n32; i += stride)
    found |= (ep[2 * i + 1] != 0);
  if (found) atomicOr(flag, 1);
}

// deg[dst]++ over all edges (in-degree; self-loop handled as +1 later)
__global__ void k_count(const int* __restrict__ ep, long long E,
                        const int* __restrict__ flag, int* __restrict__ deg) {
  int is64 = (*flag == 0);
  long long stride = (long long)gridDim.x * blockDim.x;
  for (long long e = blockIdx.x * (long long)blockDim.x + threadIdx.x; e < E;
       e += stride) {
    int d = edge_val(ep, E + e, is64);
    atomicAdd(&deg[d], 1);
  }
}

// per-block sums of deg for the 2-level scan
__global__ void k_bsum(const int* __restrict__ deg, int N,
                       int* __restrict__ bsums) {
  __shared__ int lds[TPB];
  int t = threadIdx.x;
  int i = blockIdx.x * TPB + t;
  lds[t] = (i < N) ? deg[i] : 0;
  __syncthreads();
  for (int off = TPB / 2; off > 0; off >>= 1) {
    if (t < off) lds[t] += lds[t + off];
    __syncthreads();
  }
  if (t == 0) bsums[blockIdx.x] = lds[0];
}

// single-block exclusive scan of the block sums (nb <= 512)
__global__ void k_bscan(int* __restrict__ bsums, int nb) {
  __shared__ int lds[512];
  int t = threadIdx.x;
  int v = (t < nb) ? bsums[t] : 0;
  lds[t] = v;
  __syncthreads();
  for (int off = 1; off < 512; off <<= 1) {
    int x = (t >= off) ? lds[t - off] : 0;
    __syncthreads();
    lds[t] += x;
    __syncthreads();
  }
  if (t < nb) bsums[t] = lds[t] - v;  // exclusive
}

// in-block exclusive scan + block offset -> row_start, cursor; also r = rsqrt(deg+1)
__global__ void k_scan3(const int* __restrict__ deg, const int* __restrict__ bsums,
                        int N, int* __restrict__ row_start, int* __restrict__ cursor,
                        float* __restrict__ r) {
  __shared__ int lds[TPB];
  int t = threadIdx.x;
  int i = blockIdx.x * TPB + t;
  int v = (i < N) ? deg[i] : 0;
  lds[t] = v;
  __syncthreads();
  for (int off = 1; off < TPB; off <<= 1) {
    int x = (t >= off) ? lds[t - off] : 0;
    __syncthreads();
    lds[t] += x;
    __syncthreads();
  }
  if (i < N) {
    int ex = lds[t] - v + bsums[blockIdx.x];
    row_start[i] = ex;
    cursor[i] = ex;
    r[i] = rsqrtf((float)(v + 1));
  }
}

// scatter edge src ids into CSR-by-dst
__global__ void k_fill(const int* __restrict__ ep, long long E,
                       const int* __restrict__ flag, int* __restrict__ cursor,
                       int* __restrict__ csr_src) {
  int is64 = (*flag == 0);
  long long stride = (long long)gridDim.x * blockDim.x;
  for (long long e = blockIdx.x * (long long)blockDim.x + threadIdx.x; e < E;
       e += stride) {
    int s = edge_val(ep, e, is64);
    int d = edge_val(ep, E + e, is64);
    int pos = atomicAdd(&cursor[d], 1);
    csr_src[pos] = s;
  }
}

// out[row,:] = bf16( (X[row,:] @ W) * r[row] )   (W: [128,128] row-major, in LDS)
__global__ __launch_bounds__(TPB) void k_gemm_scale(
    const float* __restrict__ X, const float* __restrict__ W,
    const float* __restrict__ r, unsigned short* __restrict__ outB, int N) {
  __shared__ float wl[128 * 128];
  for (int i = threadIdx.x; i < 128 * 128 / 4; i += TPB)
    reinterpret_cast<float4*>(wl)[i] = reinterpret_cast<const float4*>(W)[i];
  __syncthreads();
  int wave = threadIdx.x >> 6, lane = threadIdx.x & 63;
  int row0 = (blockIdx.x * 4 + wave) * 8;
  if (row0 >= N) return;
  const int c0 = lane * 2;
  float2 acc[8];
#pragma unroll
  for (int q = 0; q < 8; q++) acc[q] = make_float2(0.f, 0.f);
  for (int kk = 0; kk < 128; kk += 4) {
    float4 xv[8];
#pragma unroll
    for (int q = 0; q < 8; q++) {
      int rr = row0 + q;
      if (rr >= N) rr = N - 1;
      xv[q] = *reinterpret_cast<const float4*>(&X[(size_t)rr * 128 + kk]);
    }
#pragma unroll
    for (int u = 0; u < 4; u++) {
      float2 w = *reinterpret_cast<const float2*>(&wl[(kk + u) * 128 + c0]);
#pragma unroll
      for (int q = 0; q < 8; q++) {
        float xk = (u == 0) ? xv[q].x : (u == 1) ? xv[q].y : (u == 2) ? xv[q].z
                                                                     : xv[q].w;
        acc[q].x = fmaf(xk, w.x, acc[q].x);
        acc[q].y = fmaf(xk, w.y, acc[q].y);
      }
    }
  }
#pragma unroll
  for (int q = 0; q < 8; q++) {
    int rr = row0 + q;
    if (rr < N) {
      float sc = r[rr];
      ushort2 o;
      o.x = f2bf(acc[q].x * sc);
      o.y = f2bf(acc[q].y * sc);
      *reinterpret_cast<ushort2*>(&outB[(size_t)rr * 128 + c0]) = o;
    }
  }
}

// aggregation over bf16 table: val = act( r[i]*(Hs[i] + sum_{src->i} Hs[src]) + b )
// RELU: relu + store f32 to `out`.  COLSUM: no store, accumulate column sums.
template <int RELU, int COLSUM>
__global__ __launch_bounds__(TPB) void k_agg(
    const unsigned short* __restrict__ HsB, const float* __restrict__ r,
    const int* __restrict__ row_start, const int* __restrict__ deg,
    const int* __restrict__ csr_src, const float* __restrict__ bias,
    float* __restrict__ out, float* __restrict__ colsum, int N) {
  int wave = threadIdx.x >> 6, lane = threadIdx.x & 63;
  int gw = blockIdx.x * 4 + wave;
  int nw = gridDim.x * 4;
  const int c0 = lane * 2;
  float2 b = *reinterpret_cast<const float2*>(&bias[c0]);
  float2 csum = make_float2(0.f, 0.f);
  for (int i = gw; i < N; i += nw) {
    unsigned int self = *reinterpret_cast<const unsigned int*>(
        &HsB[(size_t)i * 128 + c0]);
    float2 acc = make_float2(bf_lo(self), bf_hi(self));
    int start = row_start[i];
    int d = deg[i];
    int j = 0;
    for (; j + 8 <= d; j += 8) {
      unsigned int vv[8];
#pragma unroll
      for (int u = 0; u < 8; u++) {
        int s = csr_src[start + j + u];
        vv[u] = *reinterpret_cast<const unsigned int*>(
            &HsB[(size_t)s * 128 + c0]);
      }
#pragma unroll
      for (int u = 0; u < 8; u++) {
        acc.x += bf_lo(vv[u]);
        acc.y += bf_hi(vv[u]);
      }
    }
    if (j + 4 <= d) {
      unsigned int vv[4];
#pragma unroll
      for (int u = 0; u < 4; u++) {
        int s = csr_src[start + j + u];
        vv[u] = *reinterpret_cast<const unsigned int*>(
            &HsB[(size_t)s * 128 + c0]);
      }
#pragma unroll
      for (int u = 0; u < 4; u++) {
        acc.x += bf_lo(vv[u]);
        acc.y += bf_hi(vv[u]);
      }
      j += 4;
    }
    for (; j < d; j++) {
      int s = csr_src[start + j];
      unsigned int v = *reinterpret_cast<const unsigned int*>(
          &HsB[(size_t)s * 128 + c0]);
      acc.x += bf_lo(v);
      acc.y += bf_hi(v);
    }
    float ri = r[i];
    float2 val = make_float2(fmaf(ri, acc.x, b.x), fmaf(ri, acc.y, b.y));
    if (RELU) {
      val.x = fmaxf(val.x, 0.f);
      val.y = fmaxf(val.y, 0.f);
    }
    if (COLSUM) {
      csum.x += val.x;
      csum.y += val.y;
    } else {
      *reinterpret_cast<float2*>(&out[(size_t)i * 128 + c0]) = val;
    }
  }
  if (COLSUM) {
    __shared__ float red[4][128];
    red[wave][c0] = csum.x;
    red[wave][c0 + 1] = csum.y;
    __syncthreads();
    if (wave == 0) {
      float sx = red[0][c0] + red[1][c0] + red[2][c0] + red[3][c0];
      float sy = red[0][c0 + 1] + red[1][c0 + 1] + red[2][c0 + 1] + red[3][c0 + 1];
      atomicAdd(&colsum[c0], sx);
      atomicAdd(&colsum[c0 + 1], sy);
    }
  }
}

__global__ void k_final(const float* __restrict__ colsum, float* __restrict__ out,
                        float invN) {
  int c = threadIdx.x;
  out[c] = colsum[c] * invN;
}

extern "C" void kernel_launch(void* const* d_in, const int* in_sizes, int n_in,
                              void* d_out, int out_size, void* d_ws, size_t ws_size,
                              hipStream_t stream) {
  const float* x = (const float*)d_in[0];
  const int* ep = (const int*)d_in[1];
  const float* W1 = (const float*)d_in[2];
  const float* b1 = (const float*)d_in[3];
  const float* W2 = (const float*)d_in[4];
  const float* b2 = (const float*)d_in[5];
  float* outp = (float*)d_out;

  const int N = in_sizes[0] / 128;        // 100000
  const long long E = in_sizes[1] / 2;    // 1600000
  const long long n32 = in_sizes[1];      // flat element count of edge_index

  // ---- workspace carve (aligned 256B) -------------------------------------
  char* ws = (char*)d_ws;
  size_t off = 0;
  auto carve = [&](size_t bytes) -> void* {
    void* p = ws + off;
    off = (off + bytes + 255) & ~(size_t)255;
    return p;
  };
  unsigned short* HsB = (unsigned short*)carve((size_t)N * 128 * 2);  // 25.6 MB
  float* Y = (float*)carve((size_t)N * 128 * 4);                      // 51.2 MB
  float* rr = (float*)carve((size_t)N * 4);
  int* deg = (int*)carve((size_t)N * 4);
  int* rs = (int*)carve((size_t)N * 4);
  int* cur = (int*)carve((size_t)N * 4);
  int* csr = (int*)carve((size_t)E * 4);                              // 6.4 MB
  int* bsums = (int*)carve(4096 * 4);
  int* flag = (int*)carve(256);
  float* colsum = (float*)carve(512);

  hipMemsetAsync(flag, 0, 4, stream);
  hipMemsetAsync(deg, 0, (size_t)N * 4, stream);
  hipMemsetAsync(colsum, 0, 512, stream);

  k_detect<<<2048, TPB, 0, stream>>>(ep, n32, flag);
  k_count<<<2048, TPB, 0, stream>>>(ep, E, flag, deg);
  int nb = (N + TPB - 1) / TPB;  // 391 <= 512
  k_bsum<<<nb, TPB, 0, stream>>>(deg, N, bsums);
  k_bscan<<<1, 512, 0, stream>>>(bsums, nb);
  k_scan3<<<nb, TPB, 0, stream>>>(deg, bsums, N, rs, cur, rr);
  k_fill<<<2048, TPB, 0, stream>>>(ep, E, flag, cur, csr);

  int gblocks = (N + 31) / 32;
  // layer 1: Hs = bf16((x@W1)*r);  Y = relu(r*(A·Hs)+b1)  (f32)
  k_gemm_scale<<<gblocks, TPB, 0, stream>>>(x, W1, rr, HsB, N);
  k_agg<1, 0><<<2048, TPB, 0, stream>>>(HsB, rr, rs, deg, csr, b1, Y, nullptr, N);
  // layer 2: Hs2 = bf16((Y@W2)*r);  colsum += r*(A·Hs2)+b2
  k_gemm_scale<<<gblocks, TPB, 0, stream>>>(Y, W2, rr, HsB, N);
  k_agg<0, 1><<<2048, TPB, 0, stream>>>(HsB, rr, rs, deg, csr, b2, nullptr, colsum, N);
  k_final<<<1, 128, 0, stream>>>(colsum, outp, 1.0f / (float)N);
}

// Round 7
// 850.601 us; speedup vs baseline: 1.1723x; 1.0358x over previous
//
#include <hip/hip_runtime.h>

#define TPB 256

typedef unsigned int uint32;
typedef unsigned int uint2v __attribute__((ext_vector_type(2)));
typedef unsigned int uint4v __attribute__((ext_vector_type(4)));
typedef float float4v __attribute__((ext_vector_type(4)));

// ---------------------------------------------------------------------------
// bf16 helpers (RTNE, bit-level; no header dependency)
// ---------------------------------------------------------------------------
static __device__ __forceinline__ unsigned short f2bf(float f) {
  unsigned int u = __float_as_uint(f);
  unsigned int r = (u + 0x7FFFu + ((u >> 16) & 1u)) >> 16;
  return (unsigned short)r;
}
static __device__ __forceinline__ float bf_lo(uint32 v) {
  return __uint_as_float(v << 16);
}
static __device__ __forceinline__ float bf_hi(uint32 v) {
  return __uint_as_float(v & 0xFFFF0000u);
}

// ---------------------------------------------------------------------------
// Edge dtype: int64 staged => odd int32 words (high words) of src row are 0.
// flag != 0  =>  int32 data.
// ---------------------------------------------------------------------------
static __device__ __forceinline__ int edge_val(const int* __restrict__ ep,
                                               long long idx, int is64) {
  return is64 ? ep[2 * idx] : ep[idx];
}

// single block: scan first min(E,16384) odd words (random node ids: all-zero
// run of 16384 words is impossible for int32 data; always zero for int64)
__global__ void k_detect(const int* __restrict__ ep, long long E,
                         int* __restrict__ flag) {
  int lim = (E < 16384) ? (int)E : 16384;
  int found = 0;
  for (int i = threadIdx.x; i < lim; i += TPB) found |= (ep[2 * i + 1] != 0);
  if (found) atomicOr(flag, 1);
}

__global__ void k_count(const int* __restrict__ ep, long long E,
                        const int* __restrict__ flag, int* __restrict__ deg) {
  int is64 = (*flag == 0);
  long long stride = (long long)gridDim.x * blockDim.x;
  for (long long e = blockIdx.x * (long long)blockDim.x + threadIdx.x; e < E;
       e += stride) {
    int d = edge_val(ep, E + e, is64);
    atomicAdd(&deg[d], 1);
  }
}

__global__ void k_bsum(const int* __restrict__ deg, int N,
                       int* __restrict__ bsums) {
  __shared__ int lds[TPB];
  int t = threadIdx.x;
  int i = blockIdx.x * TPB + t;
  lds[t] = (i < N) ? deg[i] : 0;
  __syncthreads();
  for (int off = TPB / 2; off > 0; off >>= 1) {
    if (t < off) lds[t] += lds[t + off];
    __syncthreads();
  }
  if (t == 0) bsums[blockIdx.x] = lds[0];
}

__global__ void k_bscan(int* __restrict__ bsums, int nb) {
  __shared__ int lds[512];
  int t = threadIdx.x;
  int v = (t < nb) ? bsums[t] : 0;
  lds[t] = v;
  __syncthreads();
  for (int off = 1; off < 512; off <<= 1) {
    int x = (t >= off) ? lds[t - off] : 0;
    __syncthreads();
    lds[t] += x;
    __syncthreads();
  }
  if (t < nb) bsums[t] = lds[t] - v;  // exclusive
}

__global__ void k_scan3(const int* __restrict__ deg, const int* __restrict__ bsums,
                        int N, int* __restrict__ row_start, int* __restrict__ cursor,
                        float* __restrict__ r) {
  __shared__ int lds[TPB];
  int t = threadIdx.x;
  int i = blockIdx.x * TPB + t;
  int v = (i < N) ? deg[i] : 0;
  lds[t] = v;
  __syncthreads();
  for (int off = 1; off < TPB; off <<= 1) {
    int x = (t >= off) ? lds[t - off] : 0;
    __syncthreads();
    lds[t] += x;
    __syncthreads();
  }
  if (i < N) {
    int ex = lds[t] - v + bsums[blockIdx.x];
    row_start[i] = ex;
    cursor[i] = ex;
    r[i] = rsqrtf((float)(v + 1));
  }
}

__global__ void k_fill(const int* __restrict__ ep, long long E,
                       const int* __restrict__ flag, int* __restrict__ cursor,
                       int* __restrict__ csr_src) {
  int is64 = (*flag == 0);
  long long stride = (long long)gridDim.x * blockDim.x;
  for (long long e = blockIdx.x * (long long)blockDim.x + threadIdx.x; e < E;
       e += stride) {
    int s = edge_val(ep, e, is64);
    int d = edge_val(ep, E + e, is64);
    int pos = atomicAdd(&cursor[d], 1);
    csr_src[pos] = s;
  }
}

// out[row,:] = bf16( (X@W) * r[row] ).  W packed bf16-pairs in LDS (32 KB).
// XBF=0: X is f32 (nontemporal float4 loads); XBF=1: X is bf16 rows.
template <int XBF>
__global__ __launch_bounds__(TPB, 4) void k_gemm(
    const void* __restrict__ Xv, const float* __restrict__ W,
    const float* __restrict__ r, unsigned short* __restrict__ outB, int N) {
  __shared__ uint32 wl[128 * 64];  // [k][pair] ; pair p = cols 2p,2p+1
  for (int i = threadIdx.x; i < 128 * 64; i += TPB) {
    int k = i >> 6, p = i & 63;
    float2 wv = *reinterpret_cast<const float2*>(&W[k * 128 + p * 2]);
    wl[i] = (uint32)f2bf(wv.x) | ((uint32)f2bf(wv.y) << 16);
  }
  __syncthreads();
  int wave = threadIdx.x >> 6, lane = threadIdx.x & 63;
  int row0 = (blockIdx.x * 4 + wave) * 8;
  if (row0 >= N) return;
  const int c0 = lane * 2;
  float2 acc[8];
#pragma unroll
  for (int q = 0; q < 8; q++) acc[q] = make_float2(0.f, 0.f);

  if (XBF == 0) {
    const float* X = (const float*)Xv;
    for (int kk = 0; kk < 128; kk += 4) {
      float4v xv[8];
#pragma unroll
      for (int q = 0; q < 8; q++) {
        int rr = row0 + q;
        if (rr >= N) rr = N - 1;
        xv[q] = __builtin_nontemporal_load(
            reinterpret_cast<const float4v*>(&X[(size_t)rr * 128 + kk]));
      }
#pragma unroll
      for (int u = 0; u < 4; u++) {
        uint32 wv = wl[(kk + u) * 64 + lane];
        float wx = bf_lo(wv), wy = bf_hi(wv);
#pragma unroll
        for (int q = 0; q < 8; q++) {
          float xk = xv[q][u];
          acc[q].x = fmaf(xk, wx, acc[q].x);
          acc[q].y = fmaf(xk, wy, acc[q].y);
        }
      }
    }
  } else {
    const unsigned short* X = (const unsigned short*)Xv;
    for (int kk = 0; kk < 128; kk += 8) {
      uint4v xv[8];
#pragma unroll
      for (int q = 0; q < 8; q++) {
        int rr = row0 + q;
        if (rr >= N) rr = N - 1;
        xv[q] = *reinterpret_cast<const uint4v*>(&X[(size_t)rr * 128 + kk]);
      }
#pragma unroll
      for (int u = 0; u < 8; u++) {
        uint32 wv = wl[(kk + u) * 64 + lane];
        float wx = bf_lo(wv), wy = bf_hi(wv);
#pragma unroll
        for (int q = 0; q < 8; q++) {
          uint32 xw = xv[q][u >> 1];
          float xk = (u & 1) ? bf_hi(xw) : bf_lo(xw);
          acc[q].x = fmaf(xk, wx, acc[q].x);
          acc[q].y = fmaf(xk, wy, acc[q].y);
        }
      }
    }
  }
#pragma unroll
  for (int q = 0; q < 8; q++) {
    int rr = row0 + q;
    if (rr < N) {
      float sc = r[rr];
      uint32 o = (uint32)f2bf(acc[q].x * sc) | ((uint32)f2bf(acc[q].y * sc) << 16);
      *reinterpret_cast<uint32*>(&outB[(size_t)rr * 128 + c0]) = o;
    }
  }
}

// aggregation: val = act( r[i]*(Hs[i] + sum_{src->i} Hs[src]) + b )
// 32 lanes cover a 256B row (uint2 = 4 cols/lane); lane-halves take even/odd
// edges (2 edges per vmem instr), combined via shfl_xor(32) at the end.
// RELU: store bf16 row (nontemporal). COLSUM: accumulate column sums.
template <int RELU, int COLSUM>
__global__ __launch_bounds__(TPB) void k_agg(
    const unsigned short* __restrict__ HsB, const float* __restrict__ r,
    const int* __restrict__ row_start, const int* __restrict__ deg,
    const int* __restrict__ csr_src, const float* __restrict__ bias,
    unsigned short* __restrict__ outB, float* __restrict__ colsum, int N) {
  __shared__ float red[4][128];
  int wave = threadIdx.x >> 6, lane = threadIdx.x & 63;
  int half = lane >> 5, l5 = lane & 31;
  int gw = blockIdx.x * 4 + wave, nw = gridDim.x * 4;
  const int c0 = l5 * 4;
  float4v b4 = *reinterpret_cast<const float4v*>(&bias[c0]);
  float cs0 = 0.f, cs1 = 0.f, cs2 = 0.f, cs3 = 0.f;
  for (int i = gw; i < N; i += nw) {
    float a0 = 0.f, a1 = 0.f, a2 = 0.f, a3 = 0.f;
    int start = row_start[i];
    int d = deg[i];
    if (half == 0) {
      uint2v sv = *reinterpret_cast<const uint2v*>(&HsB[(size_t)i * 128 + c0]);
      a0 = bf_lo(sv.x); a1 = bf_hi(sv.x); a2 = bf_lo(sv.y); a3 = bf_hi(sv.y);
    }
    int np = d >> 1;
    int j = 0;
    for (; j + 8 <= np; j += 8) {
      int idx[8];
#pragma unroll
      for (int u = 0; u < 8; u++) idx[u] = csr_src[start + 2 * (j + u) + half];
      uint2v vv[8];
#pragma unroll
      for (int u = 0; u < 8; u++)
        vv[u] = *reinterpret_cast<const uint2v*>(&HsB[(size_t)idx[u] * 128 + c0]);
#pragma unroll
      for (int u = 0; u < 8; u++) {
        a0 += bf_lo(vv[u].x); a1 += bf_hi(vv[u].x);
        a2 += bf_lo(vv[u].y); a3 += bf_hi(vv[u].y);
      }
    }
    for (; j < np; j++) {
      int s = csr_src[start + 2 * j + half];
      uint2v v = *reinterpret_cast<const uint2v*>(&HsB[(size_t)s * 128 + c0]);
      a0 += bf_lo(v.x); a1 += bf_hi(v.x); a2 += bf_lo(v.y); a3 += bf_hi(v.y);
    }
    if ((d & 1) && half == 0) {
      int s = csr_src[start + d - 1];
      uint2v v = *reinterpret_cast<const uint2v*>(&HsB[(size_t)s * 128 + c0]);
      a0 += bf_lo(v.x); a1 += bf_hi(v.x); a2 += bf_lo(v.y); a3 += bf_hi(v.y);
    }
    a0 += __shfl_xor(a0, 32);
    a1 += __shfl_xor(a1, 32);
    a2 += __shfl_xor(a2, 32);
    a3 += __shfl_xor(a3, 32);
    float ri = r[i];
    float v0 = fmaf(ri, a0, b4[0]), v1 = fmaf(ri, a1, b4[1]);
    float v2 = fmaf(ri, a2, b4[2]), v3 = fmaf(ri, a3, b4[3]);
    if (RELU) {
      v0 = fmaxf(v0, 0.f); v1 = fmaxf(v1, 0.f);
      v2 = fmaxf(v2, 0.f); v3 = fmaxf(v3, 0.f);
    }
    if (COLSUM) {
      if (half == 0) { cs0 += v0; cs1 += v1; cs2 += v2; cs3 += v3; }
    } else if (half == 0) {
      uint2v o;
      o.x = (uint32)f2bf(v0) | ((uint32)f2bf(v1) << 16);
      o.y = (uint32)f2bf(v2) | ((uint32)f2bf(v3) << 16);
      __builtin_nontemporal_store(
          o, reinterpret_cast<uint2v*>(&outB[(size_t)i * 128 + c0]));
    }
  }
  if (COLSUM) {
    if (half == 0) {
      red[wave][c0] = cs0; red[wave][c0 + 1] = cs1;
      red[wave][c0 + 2] = cs2; red[wave][c0 + 3] = cs3;
    }
    __syncthreads();
    if (wave == 0 && half == 0) {
#pragma unroll
      for (int c = 0; c < 4; c++) {
        float s = red[0][c0 + c] + red[1][c0 + c] + red[2][c0 + c] + red[3][c0 + c];
        atomicAdd(&colsum[c0 + c], s);
      }
    }
  }
}

__global__ void k_final(const float* __restrict__ colsum, float* __restrict__ out,
                        float invN) {
  int c = threadIdx.x;
  out[c] = colsum[c] * invN;
}

extern "C" void kernel_launch(void* const* d_in, const int* in_sizes, int n_in,
                              void* d_out, int out_size, void* d_ws, size_t ws_size,
                              hipStream_t stream) {
  const float* x = (const float*)d_in[0];
  const int* ep = (const int*)d_in[1];
  const float* W1 = (const float*)d_in[2];
  const float* b1 = (const float*)d_in[3];
  const float* W2 = (const float*)d_in[4];
  const float* b2 = (const float*)d_in[5];
  float* outp = (float*)d_out;

  const int N = in_sizes[0] / 128;      // 100000
  const long long E = in_sizes[1] / 2;  // 1600000

  char* ws = (char*)d_ws;
  size_t off = 0;
  auto carve = [&](size_t bytes) -> void* {
    void* p = ws + off;
    off = (off + bytes + 255) & ~(size_t)255;
    return p;
  };
  unsigned short* HsB = (unsigned short*)carve((size_t)N * 128 * 2);  // 25.6 MB
  unsigned short* YB = (unsigned short*)carve((size_t)N * 128 * 2);   // 25.6 MB
  float* rr = (float*)carve((size_t)N * 4);
  int* deg = (int*)carve((size_t)N * 4);
  int* rs = (int*)carve((size_t)N * 4);
  int* cur = (int*)carve((size_t)N * 4);
  int* csr = (int*)carve((size_t)E * 4);                              // 6.4 MB
  int* bsums = (int*)carve(4096 * 4);
  int* flag = (int*)carve(256);
  float* colsum = (float*)carve(512);

  hipMemsetAsync(flag, 0, 4, stream);
  hipMemsetAsync(deg, 0, (size_t)N * 4, stream);
  hipMemsetAsync(colsum, 0, 512, stream);

  k_detect<<<1, TPB, 0, stream>>>(ep, E, flag);
  k_count<<<2048, TPB, 0, stream>>>(ep, E, flag, deg);
  int nb = (N + TPB - 1) / TPB;  // 391
  k_bsum<<<nb, TPB, 0, stream>>>(deg, N, bsums);
  k_bscan<<<1, 512, 0, stream>>>(bsums, nb);
  k_scan3<<<nb, TPB, 0, stream>>>(deg, bsums, N, rs, cur, rr);
  k_fill<<<2048, TPB, 0, stream>>>(ep, E, flag, cur, csr);

  int gblocks = (N + 31) / 32;
  // layer 1: HsB = bf16((x@W1)*r);  YB = bf16(relu(r*(A·HsB)+b1))
  k_gemm<0><<<gblocks, TPB, 0, stream>>>(x, W1, rr, HsB, N);
  k_agg<1, 0><<<2048, TPB, 0, stream>>>(HsB, rr, rs, deg, csr, b1, YB, nullptr, N);
  // layer 2: HsB = bf16((YB@W2)*r);  colsum += r*(A·HsB)+b2
  k_gemm<1><<<gblocks, TPB, 0, stream>>>(YB, W2, rr, HsB, N);
  k_agg<0, 1><<<2048, TPB, 0, stream>>>(HsB, rr, rs, deg, csr, b2, nullptr, colsum, N);
  k_final<<<1, 128, 0, stream>>>(colsum, outp, 1.0f / (float)N);
}

// Round 8
// 743.958 us; speedup vs baseline: 1.3404x; 1.1433x over previous
//
#include <hip/hip_runtime.h>

#define TPB 256

typedef unsigned int uint32;
typedef float float4v __attribute__((ext_vector_type(4)));
typedef unsigned int uint4v __attribute__((ext_vector_type(4)));

// ---------------------------------------------------------------------------
// bf16 helpers (RTNE, bit-level; no header dependency)
// ---------------------------------------------------------------------------
static __device__ __forceinline__ unsigned short f2bf(float f) {
  unsigned int u = __float_as_uint(f);
  unsigned int r = (u + 0x7FFFu + ((u >> 16) & 1u)) >> 16;
  return (unsigned short)r;
}
static __device__ __forceinline__ float bf_lo(uint32 v) {
  return __uint_as_float(v << 16);
}
static __device__ __forceinline__ float bf_hi(uint32 v) {
  return __uint_as_float(v & 0xFFFF0000u);
}

// ---------------------------------------------------------------------------
// Edge dtype: int64 staged => odd int32 words (high words) of src row are 0.
// flag != 0  =>  int32 data.
// ---------------------------------------------------------------------------
static __device__ __forceinline__ int edge_val(const int* __restrict__ ep,
                                               long long idx, int is64) {
  return is64 ? ep[2 * idx] : ep[idx];
}

__global__ void k_detect(const int* __restrict__ ep, long long E,
                         int* __restrict__ flag) {
  int lim = (E < 16384) ? (int)E : 16384;
  int found = 0;
  for (int i = threadIdx.x; i < lim; i += TPB) found |= (ep[2 * i + 1] != 0);
  if (found) atomicOr(flag, 1);
}

__global__ void k_count(const int* __restrict__ ep, long long E,
                        const int* __restrict__ flag, int* __restrict__ deg) {
  int is64 = (*flag == 0);
  long long stride = (long long)gridDim.x * blockDim.x;
  for (long long e = blockIdx.x * (long long)blockDim.x + threadIdx.x; e < E;
       e += stride) {
    int d = edge_val(ep, E + e, is64);
    atomicAdd(&deg[d], 1);
  }
}

__global__ void k_bsum(const int* __restrict__ deg, int N,
                       int* __restrict__ bsums) {
  __shared__ int lds[TPB];
  int t = threadIdx.x;
  int i = blockIdx.x * TPB + t;
  lds[t] = (i < N) ? deg[i] : 0;
  __syncthreads();
  for (int off = TPB / 2; off > 0; off >>= 1) {
    if (t < off) lds[t] += lds[t + off];
    __syncthreads();
  }
  if (t == 0) bsums[blockIdx.x] = lds[0];
}

__global__ void k_bscan(int* __restrict__ bsums, int nb) {
  __shared__ int lds[512];
  int t = threadIdx.x;
  int v = (t < nb) ? bsums[t] : 0;
  lds[t] = v;
  __syncthreads();
  for (int off = 1; off < 512; off <<= 1) {
    int x = (t >= off) ? lds[t - off] : 0;
    __syncthreads();
    lds[t] += x;
    __syncthreads();
  }
  if (t < nb) bsums[t] = lds[t] - v;  // exclusive
}

__global__ void k_scan3(const int* __restrict__ deg, const int* __restrict__ bsums,
                        int N, int* __restrict__ row_start, int* __restrict__ cursor,
                        float* __restrict__ r) {
  __shared__ int lds[TPB];
  int t = threadIdx.x;
  int i = blockIdx.x * TPB + t;
  int v = (i < N) ? deg[i] : 0;
  lds[t] = v;
  __syncthreads();
  for (int off = 1; off < TPB; off <<= 1) {
    int x = (t >= off) ? lds[t - off] : 0;
    __syncthreads();
    lds[t] += x;
    __syncthreads();
  }
  if (i < N) {
    int ex = lds[t] - v + bsums[blockIdx.x];
    row_start[i] = ex;
    cursor[i] = ex;
    r[i] = rsqrtf((float)(v + 1));
  }
}

__global__ void k_fill(const int* __restrict__ ep, long long E,
                       const int* __restrict__ flag, int* __restrict__ cursor,
                       int* __restrict__ csr_src) {
  int is64 = (*flag == 0);
  long long stride = (long long)gridDim.x * blockDim.x;
  for (long long e = blockIdx.x * (long long)blockDim.x + threadIdx.x; e < E;
       e += stride) {
    int s = edge_val(ep, e, is64);
    int d = edge_val(ep, E + e, is64);
    int pos = atomicAdd(&cursor[d], 1);
    csr_src[pos] = s;
  }
}

// out[row,:] = bf16( (X@W) * r[row] ).  W packed bf16-pairs in LDS (32 KB).
// XBF=0: X is f32 (nontemporal float4 loads); XBF=1: X is bf16 rows.
template <int XBF>
__global__ __launch_bounds__(TPB, 4) void k_gemm(
    const void* __restrict__ Xv, const float* __restrict__ W,
    const float* __restrict__ r, unsigned short* __restrict__ outB, int N) {
  __shared__ uint32 wl[128 * 64];  // [k][pair] ; pair p = cols 2p,2p+1
  for (int i = threadIdx.x; i < 128 * 64; i += TPB) {
    int k = i >> 6, p = i & 63;
    float2 wv = *reinterpret_cast<const float2*>(&W[k * 128 + p * 2]);
    wl[i] = (uint32)f2bf(wv.x) | ((uint32)f2bf(wv.y) << 16);
  }
  __syncthreads();
  int wave = threadIdx.x >> 6, lane = threadIdx.x & 63;
  int row0 = (blockIdx.x * 4 + wave) * 8;
  if (row0 >= N) return;
  const int c0 = lane * 2;
  float2 acc[8];
#pragma unroll
  for (int q = 0; q < 8; q++) acc[q] = make_float2(0.f, 0.f);

  if (XBF == 0) {
    const float* X = (const float*)Xv;
    for (int kk = 0; kk < 128; kk += 4) {
      float4v xv[8];
#pragma unroll
      for (int q = 0; q < 8; q++) {
        int rr = row0 + q;
        if (rr >= N) rr = N - 1;
        xv[q] = __builtin_nontemporal_load(
            reinterpret_cast<const float4v*>(&X[(size_t)rr * 128 + kk]));
      }
#pragma unroll
      for (int u = 0; u < 4; u++) {
        uint32 wv = wl[(kk + u) * 64 + lane];
        float wx = bf_lo(wv), wy = bf_hi(wv);
#pragma unroll
        for (int q = 0; q < 8; q++) {
          float xk = xv[q][u];
          acc[q].x = fmaf(xk, wx, acc[q].x);
          acc[q].y = fmaf(xk, wy, acc[q].y);
        }
      }
    }
  } else {
    const unsigned short* X = (const unsigned short*)Xv;
    for (int kk = 0; kk < 128; kk += 8) {
      uint4v xv[8];
#pragma unroll
      for (int q = 0; q < 8; q++) {
        int rr = row0 + q;
        if (rr >= N) rr = N - 1;
        xv[q] = *reinterpret_cast<const uint4v*>(&X[(size_t)rr * 128 + kk]);
      }
#pragma unroll
      for (int u = 0; u < 8; u++) {
        uint32 wv = wl[(kk + u) * 64 + lane];
        float wx = bf_lo(wv), wy = bf_hi(wv);
#pragma unroll
        for (int q = 0; q < 8; q++) {
          uint32 xw = xv[q][u >> 1];
          float xk = (u & 1) ? bf_hi(xw) : bf_lo(xw);
          acc[q].x = fmaf(xk, wx, acc[q].x);
          acc[q].y = fmaf(xk, wy, acc[q].y);
        }
      }
    }
  }
#pragma unroll
  for (int q = 0; q < 8; q++) {
    int rr = row0 + q;
    if (rr < N) {
      float sc = r[rr];
      uint32 o = (uint32)f2bf(acc[q].x * sc) | ((uint32)f2bf(acc[q].y * sc) << 16);
      *reinterpret_cast<uint32*>(&outB[(size_t)rr * 128 + c0]) = o;
    }
  }
}

// ---------------------------------------------------------------------------
// aggregation: val = act( r[i]*(Hs[i] + sum_{src->i} Hs[src]) + b )
// Full wave per row (4B/lane = 2 bf16 cols), TWO independent nodes per wave
// interleaved (16 gathers in flight). row_start/deg readfirstlane'd so the
// csr_src batch loads are wave-uniform -> scalar s_load_dwordx-N.
// RELU: store bf16 row (nontemporal). COLSUM: accumulate column sums.
// ---------------------------------------------------------------------------
template <int RELU, int COLSUM>
__global__ __launch_bounds__(TPB) void k_agg(
    const unsigned short* __restrict__ HsB, const float* __restrict__ r,
    const int* __restrict__ row_start, const int* __restrict__ deg,
    const int* __restrict__ csr_src, const float* __restrict__ bias,
    unsigned short* __restrict__ outB, float* __restrict__ colsum, int N) {
  __shared__ float red[4][128];
  int wave = threadIdx.x >> 6, lane = threadIdx.x & 63;
  int gw = blockIdx.x * 4 + wave, nw = gridDim.x * 4;
  const int c0 = lane * 2;
  float2 b = *reinterpret_cast<const float2*>(&bias[c0]);
  float2 csum = make_float2(0.f, 0.f);

  for (int i0 = gw; i0 < N; i0 += 2 * nw) {
    const int iA = i0;
    const int iB = i0 + nw;
    const int hasB = (iB < N);
    int sA = __builtin_amdgcn_readfirstlane(row_start[iA]);
    int dA = __builtin_amdgcn_readfirstlane(deg[iA]);
    int sB = 0, dB = 0;
    if (hasB) {
      sB = __builtin_amdgcn_readfirstlane(row_start[iB]);
      dB = __builtin_amdgcn_readfirstlane(deg[iB]);
    }
    uint32 selfA = *reinterpret_cast<const uint32*>(&HsB[(size_t)iA * 128 + c0]);
    float2 aA = make_float2(bf_lo(selfA), bf_hi(selfA));
    float2 aB = make_float2(0.f, 0.f);
    if (hasB) {
      uint32 selfB = *reinterpret_cast<const uint32*>(&HsB[(size_t)iB * 128 + c0]);
      aB = make_float2(bf_lo(selfB), bf_hi(selfB));
    }
    int jA = 0, jB = 0;
    // paired 8+8 batches: 16 row-gathers in flight
    while (jA + 8 <= dA && jB + 8 <= dB) {
      int ia[8], ib[8];
#pragma unroll
      for (int u = 0; u < 8; u++) ia[u] = csr_src[sA + jA + u];
#pragma unroll
      for (int u = 0; u < 8; u++) ib[u] = csr_src[sB + jB + u];
      uint32 va[8], vb[8];
#pragma unroll
      for (int u = 0; u < 8; u++)
        va[u] = *reinterpret_cast<const uint32*>(&HsB[(size_t)ia[u] * 128 + c0]);
#pragma unroll
      for (int u = 0; u < 8; u++)
        vb[u] = *reinterpret_cast<const uint32*>(&HsB[(size_t)ib[u] * 128 + c0]);
#pragma unroll
      for (int u = 0; u < 8; u++) {
        aA.x += bf_lo(va[u]); aA.y += bf_hi(va[u]);
        aB.x += bf_lo(vb[u]); aB.y += bf_hi(vb[u]);
      }
      jA += 8; jB += 8;
    }
    // solo 8-batches
    while (jA + 8 <= dA) {
      int ia[8];
#pragma unroll
      for (int u = 0; u < 8; u++) ia[u] = csr_src[sA + jA + u];
      uint32 va[8];
#pragma unroll
      for (int u = 0; u < 8; u++)
        va[u] = *reinterpret_cast<const uint32*>(&HsB[(size_t)ia[u] * 128 + c0]);
#pragma unroll
      for (int u = 0; u < 8; u++) { aA.x += bf_lo(va[u]); aA.y += bf_hi(va[u]); }
      jA += 8;
    }
    while (jB + 8 <= dB) {
      int ib[8];
#pragma unroll
      for (int u = 0; u < 8; u++) ib[u] = csr_src[sB + jB + u];
      uint32 vb[8];
#pragma unroll
      for (int u = 0; u < 8; u++)
        vb[u] = *reinterpret_cast<const uint32*>(&HsB[(size_t)ib[u] * 128 + c0]);
#pragma unroll
      for (int u = 0; u < 8; u++) { aB.x += bf_lo(vb[u]); aB.y += bf_hi(vb[u]); }
      jB += 8;
    }
    // paired 4-batches (covers most of the 0..7 remainder)
    if (jA + 4 <= dA && jB + 4 <= dB) {
      int ia[4], ib[4];
#pragma unroll
      for (int u = 0; u < 4; u++) ia[u] = csr_src[sA + jA + u];
#pragma unroll
      for (int u = 0; u < 4; u++) ib[u] = csr_src[sB + jB + u];
      uint32 va[4], vb[4];
#pragma unroll
      for (int u = 0; u < 4; u++)
        va[u] = *reinterpret_cast<const uint32*>(&HsB[(size_t)ia[u] * 128 + c0]);
#pragma unroll
      for (int u = 0; u < 4; u++)
        vb[u] = *reinterpret_cast<const uint32*>(&HsB[(size_t)ib[u] * 128 + c0]);
#pragma unroll
      for (int u = 0; u < 4; u++) {
        aA.x += bf_lo(va[u]); aA.y += bf_hi(va[u]);
        aB.x += bf_lo(vb[u]); aB.y += bf_hi(vb[u]);
      }
      jA += 4; jB += 4;
    }
    if (jA + 4 <= dA) {
      int ia[4];
#pragma unroll
      for (int u = 0; u < 4; u++) ia[u] = csr_src[sA + jA + u];
      uint32 va[4];
#pragma unroll
      for (int u = 0; u < 4; u++)
        va[u] = *reinterpret_cast<const uint32*>(&HsB[(size_t)ia[u] * 128 + c0]);
#pragma unroll
      for (int u = 0; u < 4; u++) { aA.x += bf_lo(va[u]); aA.y += bf_hi(va[u]); }
      jA += 4;
    }
    if (jB + 4 <= dB) {
      int ib[4];
#pragma unroll
      for (int u = 0; u < 4; u++) ib[u] = csr_src[sB + jB + u];
      uint32 vb[4];
#pragma unroll
      for (int u = 0; u < 4; u++)
        vb[u] = *reinterpret_cast<const uint32*>(&HsB[(size_t)ib[u] * 128 + c0]);
#pragma unroll
      for (int u = 0; u < 4; u++) { aB.x += bf_lo(vb[u]); aB.y += bf_hi(vb[u]); }
      jB += 4;
    }
    // scalar tails (<=3 each), interleaved
    for (; jA < dA && jB < dB; jA++, jB++) {
      int s0 = csr_src[sA + jA], s1 = csr_src[sB + jB];
      uint32 v0 = *reinterpret_cast<const uint32*>(&HsB[(size_t)s0 * 128 + c0]);
      uint32 v1 = *reinterpret_cast<const uint32*>(&HsB[(size_t)s1 * 128 + c0]);
      aA.x += bf_lo(v0); aA.y += bf_hi(v0);
      aB.x += bf_lo(v1); aB.y += bf_hi(v1);
    }
    for (; jA < dA; jA++) {
      int s0 = csr_src[sA + jA];
      uint32 v0 = *reinterpret_cast<const uint32*>(&HsB[(size_t)s0 * 128 + c0]);
      aA.x += bf_lo(v0); aA.y += bf_hi(v0);
    }
    for (; jB < dB; jB++) {
      int s1 = csr_src[sB + jB];
      uint32 v1 = *reinterpret_cast<const uint32*>(&HsB[(size_t)s1 * 128 + c0]);
      aB.x += bf_lo(v1); aB.y += bf_hi(v1);
    }
    // epilogue A
    {
      float ri = r[iA];
      float v0 = fmaf(ri, aA.x, b.x), v1 = fmaf(ri, aA.y, b.y);
      if (RELU) { v0 = fmaxf(v0, 0.f); v1 = fmaxf(v1, 0.f); }
      if (COLSUM) {
        csum.x += v0; csum.y += v1;
      } else {
        uint32 o = (uint32)f2bf(v0) | ((uint32)f2bf(v1) << 16);
        __builtin_nontemporal_store(
            o, reinterpret_cast<uint32*>(&outB[(size_t)iA * 128 + c0]));
      }
    }
    // epilogue B
    if (hasB) {
      float ri = r[iB];
      float v0 = fmaf(ri, aB.x, b.x), v1 = fmaf(ri, aB.y, b.y);
      if (RELU) { v0 = fmaxf(v0, 0.f); v1 = fmaxf(v1, 0.f); }
      if (COLSUM) {
        csum.x += v0; csum.y += v1;
      } else {
        uint32 o = (uint32)f2bf(v0) | ((uint32)f2bf(v1) << 16);
        __builtin_nontemporal_store(
            o, reinterpret_cast<uint32*>(&outB[(size_t)iB * 128 + c0]));
      }
    }
  }
  if (COLSUM) {
    red[wave][c0] = csum.x;
    red[wave][c0 + 1] = csum.y;
    __syncthreads();
    if (wave == 0) {
      float sx = red[0][c0] + red[1][c0] + red[2][c0] + red[3][c0];
      float sy = red[0][c0 + 1] + red[1][c0 + 1] + red[2][c0 + 1] + red[3][c0 + 1];
      atomicAdd(&colsum[c0], sx);
      atomicAdd(&colsum[c0 + 1], sy);
    }
  }
}

__global__ void k_final(const float* __restrict__ colsum, float* __restrict__ out,
                        float invN) {
  int c = threadIdx.x;
  out[c] = colsum[c] * invN;
}

extern "C" void kernel_launch(void* const* d_in, const int* in_sizes, int n_in,
                              void* d_out, int out_size, void* d_ws, size_t ws_size,
                              hipStream_t stream) {
  const float* x = (const float*)d_in[0];
  const int* ep = (const int*)d_in[1];
  const float* W1 = (const float*)d_in[2];
  const float* b1 = (const float*)d_in[3];
  const float* W2 = (const float*)d_in[4];
  const float* b2 = (const float*)d_in[5];
  float* outp = (float*)d_out;

  const int N = in_sizes[0] / 128;      // 100000
  const long long E = in_sizes[1] / 2;  // 1600000

  char* ws = (char*)d_ws;
  size_t off = 0;
  auto carve = [&](size_t bytes) -> void* {
    void* p = ws + off;
    off = (off + bytes + 255) & ~(size_t)255;
    return p;
  };
  unsigned short* HsB = (unsigned short*)carve((size_t)N * 128 * 2);  // 25.6 MB
  unsigned short* YB = (unsigned short*)carve((size_t)N * 128 * 2);   // 25.6 MB
  float* rr = (float*)carve((size_t)N * 4);
  int* deg = (int*)carve((size_t)N * 4);
  int* rs = (int*)carve((size_t)N * 4);
  int* cur = (int*)carve((size_t)N * 4);
  int* csr = (int*)carve((size_t)E * 4);                              // 6.4 MB
  int* bsums = (int*)carve(4096 * 4);
  int* flag = (int*)carve(256);
  float* colsum = (float*)carve(512);

  hipMemsetAsync(flag, 0, 4, stream);
  hipMemsetAsync(deg, 0, (size_t)N * 4, stream);
  hipMemsetAsync(colsum, 0, 512, stream);

  k_detect<<<1, TPB, 0, stream>>>(ep, E, flag);
  k_count<<<2048, TPB, 0, stream>>>(ep, E, flag, deg);
  int nb = (N + TPB - 1) / TPB;  // 391
  k_bsum<<<nb, TPB, 0, stream>>>(deg, N, bsums);
  k_bscan<<<1, 512, 0, stream>>>(bsums, nb);
  k_scan3<<<nb, TPB, 0, stream>>>(deg, bsums, N, rs, cur, rr);
  k_fill<<<2048, TPB, 0, stream>>>(ep, E, flag, cur, csr);

  int gblocks = (N + 31) / 32;
  // layer 1: HsB = bf16((x@W1)*r);  YB = bf16(relu(r*(A·HsB)+b1))
  k_gemm<0><<<gblocks, TPB, 0, stream>>>(x, W1, rr, HsB, N);
  k_agg<1, 0><<<2048, TPB, 0, stream>>>(HsB, rr, rs, deg, csr, b1, YB, nullptr, N);
  // layer 2: HsB = bf16((YB@W2)*r);  colsum += r*(A·HsB)+b2
  k_gemm<1><<<gblocks, TPB, 0, stream>>>(YB, W2, rr, HsB, N);
  k_agg<0, 1><<<2048, TPB, 0, stream>>>(HsB, rr, rs, deg, csr, b2, nullptr, colsum, N);
  k_final<<<1, 128, 0, stream>>>(colsum, outp, 1.0f / (float)N);
}